// Round 2
// baseline (404.601 us; speedup 1.0000x reference)
//
#include <hip/hip_runtime.h>
#include <stdint.h>

using short8  = __attribute__((ext_vector_type(8))) short;
using float4_ = __attribute__((ext_vector_type(4))) float;
typedef unsigned int  uint;
typedef unsigned short ushort;

// ---------- bf16 helpers ----------
__device__ __forceinline__ float bf2f(ushort b) {
  uint u = ((uint)b) << 16;
  return __builtin_bit_cast(float, u);
}
__device__ __forceinline__ ushort f2bf(float f) {
  uint u = __builtin_bit_cast(uint, f);
  u = u + 0x7fffu + ((u >> 16) & 1u);   // RTNE
  return (ushort)(u >> 16);
}

// ---------- constants ----------
#define NN   216      // tokens (6*6*6)
#define NSQ  46656    // 216*216

// weight arena element offsets (order: Wqkv,bqkv,Wproj,bproj, then 14 pos arrays)
#define WA_WQKV   0
#define WA_BQKV   110592
#define WA_WPROJ  111168
#define WA_BPROJ  148032
#define WA_PPW    148224
#define WA_PPB    148260
#define WA_G1     148272
#define WA_B1     148284
#define WA_W1     148296
#define WA_WB1    148440
#define WA_G2     148452
#define WA_B2     148464
#define WA_W2     148476
#define WA_WB2    148620
#define WA_G3     148632
#define WA_B3     148644
#define WA_W3     148656
#define WA_WB3    148728
#define WA_TOTAL  148740

// =====================================================================
// 0) dtype detector: flag = 0 (bf16 inputs) / 1 (fp32 inputs)
// =====================================================================
__global__ void detect_kernel(const uint* __restrict__ x, int* __restrict__ flag) {
  int lane = threadIdx.x;
  uint w = x[lane];
  ushort lo = (ushort)(w & 0xffffu);
  int e = (lo >> 7) & 0xff;
  int sane = (lo == 0 || (e >= 0x60 && e <= 0x9f)) ? 1 : 0;
  unsigned long long b = __ballot(sane);
  if (lane == 0) flag[0] = (__popcll(b) >= 56) ? 0 : 1;
}

// =====================================================================
// 0b) weight conversion into canonical bf16 arena
// =====================================================================
struct SrcPtrs { const void* p[18]; };

__global__ void convert_kernel(SrcPtrs sp, ushort* __restrict__ dst,
                               const int* __restrict__ flag) {
  constexpr int OFF[19] = {WA_WQKV, WA_BQKV, WA_WPROJ, WA_BPROJ, WA_PPW, WA_PPB,
                           WA_G1, WA_B1, WA_W1, WA_WB1, WA_G2, WA_B2, WA_W2,
                           WA_WB2, WA_G3, WA_B3, WA_W3, WA_WB3, WA_TOTAL};
  int t = blockIdx.x * 256 + threadIdx.x;
  if (t >= WA_TOTAL) return;
  int a = 0;
#pragma unroll
  for (int i = 1; i < 18; ++i) a += (t >= OFF[i]) ? 1 : 0;
  int local = t - OFF[a];
  const void* s = sp.p[a];
  ushort v;
  if (flag[0]) v = f2bf(((const float*)s)[local]);
  else         v = ((const ushort*)s)[local];
  dst[t] = v;
}

// =====================================================================
// 1) pos MLP: offsets (1331,3) -> pos (1331, 6)   [fp32 out]
// =====================================================================
__device__ __forceinline__ void ln_relu(const float* p, const ushort* g,
                                        const ushort* b, float* r) {
  float m = 0.f;
#pragma unroll
  for (int t = 0; t < 12; ++t) m += p[t];
  m *= (1.f / 12.f);
  float v = 0.f;
#pragma unroll
  for (int t = 0; t < 12; ++t) { float d = p[t] - m; v += d * d; }
  v *= (1.f / 12.f);
  float inv = rsqrtf(v + 1e-5f);
#pragma unroll
  for (int t = 0; t < 12; ++t) {
    float z = (p[t] - m) * inv * bf2f(g[t]) + bf2f(b[t]);
    r[t] = fmaxf(z, 0.f);
  }
}

__global__ void pos_mlp_kernel(const ushort* __restrict__ wa, float* __restrict__ pos) {
  int m = blockIdx.x * blockDim.x + threadIdx.x;
  if (m >= 1331) return;
  const ushort* pw  = wa + WA_PPW;  const ushort* pb  = wa + WA_PPB;
  const ushort* g1  = wa + WA_G1;   const ushort* b1  = wa + WA_B1;
  const ushort* w1  = wa + WA_W1;   const ushort* wb1 = wa + WA_WB1;
  const ushort* g2  = wa + WA_G2;   const ushort* b2  = wa + WA_B2;
  const ushort* w2  = wa + WA_W2;   const ushort* wb2 = wa + WA_WB2;
  const ushort* g3  = wa + WA_G3;   const ushort* b3  = wa + WA_B3;
  const ushort* w3  = wa + WA_W3;   const ushort* wb3 = wa + WA_WB3;

  int ih = m / 121, rem = m - ih * 121;
  int iw = rem / 11, id = rem - iw * 11;
  float fh = (float)(ih - 5), fw = (float)(iw - 5), fd = (float)(id - 5);
  float p[12], r[12], q[12];
#pragma unroll
  for (int t = 0; t < 12; ++t)
    p[t] = fh * bf2f(pw[t * 3]) + fw * bf2f(pw[t * 3 + 1]) +
           fd * bf2f(pw[t * 3 + 2]) + bf2f(pb[t]);
  ln_relu(p, g1, b1, r);
#pragma unroll
  for (int t = 0; t < 12; ++t) {
    float s = bf2f(wb1[t]);
#pragma unroll
    for (int u = 0; u < 12; ++u) s += r[u] * bf2f(w1[t * 12 + u]);
    q[t] = s;
  }
  ln_relu(q, g2, b2, r);
#pragma unroll
  for (int t = 0; t < 12; ++t) {
    float s = bf2f(wb2[t]);
#pragma unroll
    for (int u = 0; u < 12; ++u) s += r[u] * bf2f(w2[t * 12 + u]);
    p[t] = s;
  }
  ln_relu(p, g3, b3, r);
#pragma unroll
  for (int h = 0; h < 6; ++h) {
    float s = bf2f(wb3[h]);
#pragma unroll
    for (int u = 0; u < 12; ++u) s += r[u] * bf2f(w3[h * 12 + u]);
    pos[m * 6 + h] = s;
  }
}

// =====================================================================
// 2) rpb gather: rpb[h][i][j] = pos[idx(i,j)][h]   (fp32)
// =====================================================================
__global__ void rpb_kernel(const float* __restrict__ pos, float* __restrict__ rpb) {
  int t = blockIdx.x * 256 + threadIdx.x;
  if (t >= NSQ) return;
  int i = t / 216, j = t - i * 216;
  int h1 = i / 36, r1 = i - h1 * 36, w1 = r1 / 6, d1 = r1 - w1 * 6;
  int h2 = j / 36, r2 = j - h2 * 36, w2 = r2 / 6, d2 = r2 - w2 * 6;
  int idx = ((h1 - h2 + 5) * 11 + (w1 - w2 + 5)) * 11 + (d1 - d2 + 5);
#pragma unroll
  for (int h = 0; h < 6; ++h) rpb[h * NSQ + t] = pos[idx * 6 + h];
}

// =====================================================================
// 3) GEMM (M=55296, K=192) x W^T(rows wbase..wbase+63) + bias
// =====================================================================
__global__ __launch_bounds__(256) void gemm_kernel(
    const void* __restrict__ Ax, const void* __restrict__ Ay,
    const ushort* __restrict__ W,  const ushort* __restrict__ bias,
    void* __restrict__ dq, void* __restrict__ dk, void* __restrict__ dv,
    const int* __restrict__ flag, int is_proj) {
  __shared__ __align__(16) ushort a_lds[128 * 104];
  __shared__ __align__(16) ushort b_lds[64 * 104];
  int tid = threadIdx.x;
  int m0 = blockIdx.x * 128;
  int by = blockIdx.y;
  int z  = blockIdx.z;
  const void* A = (z == 0) ? Ax : Ay;
  int wbase = (is_proj ? 0 : z * 192) + by * 64;
  float scale = (!is_proj && z == 0) ? 0.17677669529663687f : 1.0f;
  void* dst = (z == 0) ? dq : (z == 1 ? dk : dv);
  bool a_f32 = (!is_proj) && (flag[0] != 0);   // internal buffers always bf16
  bool o_f32 = is_proj && (flag[0] != 0);

  int lane = tid & 63, w = tid >> 6;
  int l16 = lane & 15, quad = lane >> 4;
  int wm = w >> 1, wn = w & 1;

  float4_ acc[4][2];
#pragma unroll
  for (int mt = 0; mt < 4; ++mt)
#pragma unroll
    for (int nt = 0; nt < 2; ++nt) acc[mt][nt] = (float4_){0.f, 0.f, 0.f, 0.f};

  for (int kc = 0; kc < 2; ++kc) {
    for (int i = tid; i < 1536; i += 256) {
      int row = i / 12, c8 = i - row * 12;
      short8 pk;
      if (a_f32) {
        const float* Af = (const float*)A + (size_t)(m0 + row) * 192 + kc * 96 + c8 * 8;
        float4_ lo = *(const float4_*)Af;
        float4_ hi = *(const float4_*)(Af + 4);
#pragma unroll
        for (int jj = 0; jj < 4; ++jj) {
          pk[jj]     = (short)f2bf(lo[jj]);
          pk[4 + jj] = (short)f2bf(hi[jj]);
        }
      } else {
        pk = *(const short8*)((const ushort*)A + (size_t)(m0 + row) * 192 + kc * 96 + c8 * 8);
      }
      *(short8*)(a_lds + row * 104 + c8 * 8) = pk;
    }
    for (int i = tid; i < 768; i += 256) {
      int row = i / 12, c8 = i - row * 12;
      short8 pk = *(const short8*)(W + (size_t)(wbase + row) * 192 + kc * 96 + c8 * 8);
      *(short8*)(b_lds + row * 104 + c8 * 8) = pk;
    }
    __syncthreads();
#pragma unroll
    for (int kk = 0; kk < 3; ++kk) {
      short8 af[4], bf[2];
#pragma unroll
      for (int mt = 0; mt < 4; ++mt)
        af[mt] = *(const short8*)(a_lds + (wm * 64 + mt * 16 + l16) * 104 + kk * 32 + quad * 8);
#pragma unroll
      for (int nt = 0; nt < 2; ++nt)
        bf[nt] = *(const short8*)(b_lds + (wn * 32 + nt * 16 + l16) * 104 + kk * 32 + quad * 8);
#pragma unroll
      for (int mt = 0; mt < 4; ++mt)
#pragma unroll
        for (int nt = 0; nt < 2; ++nt)
          acc[mt][nt] = __builtin_amdgcn_mfma_f32_16x16x32_bf16(af[mt], bf[nt], acc[mt][nt], 0, 0, 0);
    }
    __syncthreads();
  }

#pragma unroll
  for (int mt = 0; mt < 4; ++mt) {
#pragma unroll
    for (int nt = 0; nt < 2; ++nt) {
      int lcol = by * 64 + wn * 32 + nt * 16 + l16;   // 0..191
      float bv = bf2f(bias[(is_proj ? 0 : z * 192) + lcol]);
#pragma unroll
      for (int r = 0; r < 4; ++r) {
        int grow = m0 + wm * 64 + mt * 16 + quad * 4 + r;
        float val = (acc[mt][nt][r] + bv) * scale;
        if (is_proj) {
          if (o_f32) ((float*)dst)[(size_t)grow * 192 + lcol] = val;
          else       ((ushort*)dst)[(size_t)grow * 192 + lcol] = f2bf(val);
        } else {
          int bb = grow / 216;
          int nn2 = grow - bb * 216;
          int hh = lcol >> 5, dd = lcol & 31;
          ((ushort*)dst)[(((size_t)bb * 6 + hh) * 216 + nn2) * 32 + dd] = f2bf(val);
        }
      }
    }
  }
}

// =====================================================================
// 4) fused attention: one WG (4 waves) per (b, h)
// =====================================================================
__global__ __launch_bounds__(256) void attn_kernel(
    const ushort* __restrict__ q, const ushort* __restrict__ k,
    const ushort* __restrict__ v, const float* __restrict__ rpb,
    const void* __restrict__ maskv, const int* __restrict__ flag,
    ushort* __restrict__ opre) {
  __shared__ __align__(16) ushort vts[32 * 232];     // v^T, padded cols
  __shared__ __align__(16) ushort ps[4][16 * 232];   // per-wave P tile

  int bid = blockIdx.x;
  int b = bid / 6, h = bid - b * 6;
  int g = b & 63;
  int tid = threadIdx.x, lane = tid & 63, w = tid >> 6;
  int l16 = lane & 15, quad = lane >> 4;
  bool mf32 = flag[0] != 0;

  const ushort* qh = q + (size_t)(b * 6 + h) * 6912;
  const ushort* kh = k + (size_t)(b * 6 + h) * 6912;
  const ushort* vh = v + (size_t)(b * 6 + h) * 6912;
  const float*  rh = rpb + (size_t)h * NSQ;
  const float*  mhf = (const float*)maskv + (size_t)g * NSQ;
  const ushort* mhu = (const ushort*)maskv + (size_t)g * NSQ;

  // zero vts (pad cols must be 0), then transpose v into it
  for (int i = tid; i < (32 * 232) / 2; i += 256) ((uint*)vts)[i] = 0u;
  __syncthreads();
  for (int i = tid; i < 864; i += 256) {
    int n = i >> 2, dp = (i & 3) * 8;
    uint4 raw = *(const uint4*)(vh + n * 32 + dp);
    const ushort* ep = reinterpret_cast<const ushort*>(&raw);
#pragma unroll
    for (int jj = 0; jj < 8; ++jj) vts[(dp + jj) * 232 + n] = ep[jj];
  }
  __syncthreads();

  for (int t = w; t < 14; t += 4) {
    int r0 = t * 16;
    short8 aq = *(const short8*)(qh + (r0 + l16) * 32 + quad * 8);

    float4_ s[14];
#pragma unroll
    for (int j = 0; j < 14; ++j) {
      short8 bk = *(const short8*)(kh + (j * 16 + l16) * 32 + quad * 8);
      s[j] = __builtin_amdgcn_mfma_f32_16x16x32_bf16(aq, bk, (float4_){0.f, 0.f, 0.f, 0.f}, 0, 0, 0);
    }

#pragma unroll
    for (int j = 0; j < 14; ++j) {
      int col = j * 16 + l16;
      bool cv = col < 216;
#pragma unroll
      for (int r = 0; r < 4; ++r) {
        int i = r0 + quad * 4 + r;
        int gi = i < 216 ? i : 215;
        float val = -1e9f;
        if (cv) {
          int mi = gi * 216 + col;
          float mval = mf32 ? mhf[mi] : bf2f(mhu[mi]);
          val = s[j][r] + rh[mi] + mval;
        }
        s[j][r] = val;
      }
    }

#pragma unroll
    for (int r = 0; r < 4; ++r) {
      float mx = -1e30f;
#pragma unroll
      for (int j = 0; j < 14; ++j) mx = fmaxf(mx, s[j][r]);
      mx = fmaxf(mx, __shfl_xor(mx, 1));
      mx = fmaxf(mx, __shfl_xor(mx, 2));
      mx = fmaxf(mx, __shfl_xor(mx, 4));
      mx = fmaxf(mx, __shfl_xor(mx, 8));
      float sum = 0.f;
#pragma unroll
      for (int j = 0; j < 14; ++j) {
        float pe = __expf(s[j][r] - mx);
        s[j][r] = pe;
        sum += pe;
      }
      sum += __shfl_xor(sum, 1);
      sum += __shfl_xor(sum, 2);
      sum += __shfl_xor(sum, 4);
      sum += __shfl_xor(sum, 8);
      float inv = 1.0f / sum;
#pragma unroll
      for (int j = 0; j < 14; ++j)
        ps[w][(quad * 4 + r) * 232 + j * 16 + l16] = f2bf(s[j][r] * inv);
    }

    float4_ o0 = (float4_){0.f, 0.f, 0.f, 0.f};
    float4_ o1 = (float4_){0.f, 0.f, 0.f, 0.f};
#pragma unroll
    for (int kt = 0; kt < 7; ++kt) {
      short8 pf = *(const short8*)(&ps[w][l16 * 232 + kt * 32 + quad * 8]);
      short8 v0 = *(const short8*)(&vts[(l16) * 232 + kt * 32 + quad * 8]);
      short8 v1 = *(const short8*)(&vts[(16 + l16) * 232 + kt * 32 + quad * 8]);
      o0 = __builtin_amdgcn_mfma_f32_16x16x32_bf16(pf, v0, o0, 0, 0, 0);
      o1 = __builtin_amdgcn_mfma_f32_16x16x32_bf16(pf, v1, o1, 0, 0, 0);
    }

#pragma unroll
    for (int r = 0; r < 4; ++r) {
      int i = r0 + quad * 4 + r;
      if (i < 216) {
        size_t base = ((size_t)b * 216 + i) * 192 + h * 32;
        opre[base + l16]      = f2bf(o0[r]);
        opre[base + 16 + l16] = f2bf(o1[r]);
      }
    }
  }
}

// =====================================================================
// launch
// =====================================================================
extern "C" void kernel_launch(void* const* d_in, const int* in_sizes, int n_in,
                              void* d_out, int out_size, void* d_ws, size_t ws_size,
                              hipStream_t stream) {
  (void)in_sizes; (void)n_in; (void)out_size; (void)ws_size;

  char* p = (char*)d_ws;
  int*    flag   = (int*)p;            p += 256;
  ushort* warena = (ushort*)p;         p += 298496 - 256;
  float*  pos    = (float*)p;          p += 32000;
  float*  rpb    = (float*)p;          p += (size_t)6 * NSQ * 4;   // 1,119,744
  ushort* qb     = (ushort*)p;         p += 21234688;
  ushort* kb     = (ushort*)p;         p += 21234688;
  ushort* vb     = (ushort*)p;         p += 21234688;
  ushort* opre   = (ushort*)p;

  detect_kernel<<<1, 64, 0, stream>>>((const uint*)d_in[0], flag);

  SrcPtrs sp;
  for (int i = 0; i < 18; ++i) sp.p[i] = d_in[3 + i];
  convert_kernel<<<(WA_TOTAL + 255) / 256, 256, 0, stream>>>(sp, warena, flag);

  pos_mlp_kernel<<<6, 256, 0, stream>>>(warena, pos);
  rpb_kernel<<<183, 256, 0, stream>>>(pos, rpb);

  gemm_kernel<<<dim3(432, 3, 3), 256, 0, stream>>>(
      d_in[0], d_in[1], warena + WA_WQKV, warena + WA_BQKV,
      qb, kb, vb, flag, 0);

  attn_kernel<<<1536, 256, 0, stream>>>(qb, kb, vb, rpb, d_in[2], flag, opre);

  gemm_kernel<<<dim3(432, 3, 1), 256, 0, stream>>>(
      opre, opre, warena + WA_WPROJ, warena + WA_BPROJ,
      d_out, d_out, d_out, flag, 1);
}

// Round 3
// 336.397 us; speedup vs baseline: 1.2027x; 1.2027x over previous
//
#include <hip/hip_runtime.h>
#include <stdint.h>

using short8   = __attribute__((ext_vector_type(8))) short;
using float4_  = __attribute__((ext_vector_type(4))) float;
using ushort4_ = __attribute__((ext_vector_type(4))) unsigned short;
typedef unsigned int  uint;
typedef unsigned short ushort;

// ---------- bf16 helpers ----------
__device__ __forceinline__ float bf2f(ushort b) {
  uint u = ((uint)b) << 16;
  return __builtin_bit_cast(float, u);
}
__device__ __forceinline__ ushort f2bf(float f) {
  uint u = __builtin_bit_cast(uint, f);
  u = u + 0x7fffu + ((u >> 16) & 1u);   // RTNE
  return (ushort)(u >> 16);
}

// ---------- constants ----------
#define NN   216      // tokens (6*6*6)
#define NSQ  46656    // 216*216
#define PADV (-3.0e6f)

// weight arena element offsets
#define WA_WQKV   0
#define WA_BQKV   110592
#define WA_WPROJ  111168
#define WA_BPROJ  148032
#define WA_PPW    148224
#define WA_PPB    148260
#define WA_G1     148272
#define WA_B1     148284
#define WA_W1     148296
#define WA_WB1    148440
#define WA_G2     148452
#define WA_B2     148464
#define WA_W2     148476
#define WA_WB2    148620
#define WA_G3     148632
#define WA_B3     148644
#define WA_W3     148656
#define WA_WB3    148728
#define WA_TOTAL  148740

// =====================================================================
// 0) dtype detector: flag = 0 (bf16 inputs) / 1 (fp32 inputs)
// =====================================================================
__global__ void detect_kernel(const uint* __restrict__ x, int* __restrict__ flag) {
  int lane = threadIdx.x;
  uint w = x[lane];
  ushort lo = (ushort)(w & 0xffffu);
  int e = (lo >> 7) & 0xff;
  int sane = (lo == 0 || (e >= 0x60 && e <= 0x9f)) ? 1 : 0;
  unsigned long long b = __ballot(sane);
  if (lane == 0) flag[0] = (__popcll(b) >= 56) ? 0 : 1;
}

// =====================================================================
// 0b) weight conversion into canonical bf16 arena
// =====================================================================
struct SrcPtrs { const void* p[18]; };

__global__ void convert_kernel(SrcPtrs sp, ushort* __restrict__ dst,
                               const int* __restrict__ flag) {
  constexpr int OFF[19] = {WA_WQKV, WA_BQKV, WA_WPROJ, WA_BPROJ, WA_PPW, WA_PPB,
                           WA_G1, WA_B1, WA_W1, WA_WB1, WA_G2, WA_B2, WA_W2,
                           WA_WB2, WA_G3, WA_B3, WA_W3, WA_WB3, WA_TOTAL};
  int t = blockIdx.x * 256 + threadIdx.x;
  if (t >= WA_TOTAL) return;
  int a = 0;
#pragma unroll
  for (int i = 1; i < 18; ++i) a += (t >= OFF[i]) ? 1 : 0;
  int local = t - OFF[a];
  const void* s = sp.p[a];
  ushort v;
  if (flag[0]) v = f2bf(((const float*)s)[local]);
  else         v = ((const ushort*)s)[local];
  dst[t] = v;
}

// =====================================================================
// 1) pos MLP: offsets (1331,3) -> pos (1331, 6)   [fp32 out]
// =====================================================================
__device__ __forceinline__ void ln_relu(const float* p, const ushort* g,
                                        const ushort* b, float* r) {
  float m = 0.f;
#pragma unroll
  for (int t = 0; t < 12; ++t) m += p[t];
  m *= (1.f / 12.f);
  float v = 0.f;
#pragma unroll
  for (int t = 0; t < 12; ++t) { float d = p[t] - m; v += d * d; }
  v *= (1.f / 12.f);
  float inv = rsqrtf(v + 1e-5f);
#pragma unroll
  for (int t = 0; t < 12; ++t) {
    float z = (p[t] - m) * inv * bf2f(g[t]) + bf2f(b[t]);
    r[t] = fmaxf(z, 0.f);
  }
}

__global__ void pos_mlp_kernel(const ushort* __restrict__ wa, float* __restrict__ pos) {
  int m = blockIdx.x * blockDim.x + threadIdx.x;
  if (m >= 1331) return;
  const ushort* pw  = wa + WA_PPW;  const ushort* pb  = wa + WA_PPB;
  const ushort* g1  = wa + WA_G1;   const ushort* b1  = wa + WA_B1;
  const ushort* w1  = wa + WA_W1;   const ushort* wb1 = wa + WA_WB1;
  const ushort* g2  = wa + WA_G2;   const ushort* b2  = wa + WA_B2;
  const ushort* w2  = wa + WA_W2;   const ushort* wb2 = wa + WA_WB2;
  const ushort* g3  = wa + WA_G3;   const ushort* b3  = wa + WA_B3;
  const ushort* w3  = wa + WA_W3;   const ushort* wb3 = wa + WA_WB3;

  int ih = m / 121, rem = m - ih * 121;
  int iw = rem / 11, id = rem - iw * 11;
  float fh = (float)(ih - 5), fw = (float)(iw - 5), fd = (float)(id - 5);
  float p[12], r[12], q[12];
#pragma unroll
  for (int t = 0; t < 12; ++t)
    p[t] = fh * bf2f(pw[t * 3]) + fw * bf2f(pw[t * 3 + 1]) +
           fd * bf2f(pw[t * 3 + 2]) + bf2f(pb[t]);
  ln_relu(p, g1, b1, r);
#pragma unroll
  for (int t = 0; t < 12; ++t) {
    float s = bf2f(wb1[t]);
#pragma unroll
    for (int u = 0; u < 12; ++u) s += r[u] * bf2f(w1[t * 12 + u]);
    q[t] = s;
  }
  ln_relu(q, g2, b2, r);
#pragma unroll
  for (int t = 0; t < 12; ++t) {
    float s = bf2f(wb2[t]);
#pragma unroll
    for (int u = 0; u < 12; ++u) s += r[u] * bf2f(w2[t * 12 + u]);
    p[t] = s;
  }
  ln_relu(p, g3, b3, r);
#pragma unroll
  for (int h = 0; h < 6; ++h) {
    float s = bf2f(wb3[h]);
#pragma unroll
    for (int u = 0; u < 12; ++u) s += r[u] * bf2f(w3[h * 12 + u]);
    pos[m * 6 + h] = s;
  }
}

// =====================================================================
// 2a) rpb fragments: per head, MFMA C-layout, bf16
//     elem index = ((h*196 + t*14 + j)*64 + lane)*4 + r
// =====================================================================
__global__ void rpbfrag_kernel(const float* __restrict__ pos, ushort* __restrict__ out) {
  int tgl = blockIdx.x * 256 + threadIdx.x;
  if (tgl >= 6 * 196 * 64) return;
  int lane = tgl & 63;
  int tj   = (tgl >> 6) % 196;
  int h    = (tgl >> 6) / 196;
  int tt = tj / 14, j = tj - tt * 14;
  int l16 = lane & 15, quad = lane >> 4;
  int col = j * 16 + l16;
  int h2 = col / 36, r2 = col - h2 * 36, w2 = r2 / 6, d2 = r2 - w2 * 6;
  ushort4_ o;
#pragma unroll
  for (int r = 0; r < 4; ++r) {
    int i = tt * 16 + quad * 4 + r;
    float val = PADV;
    if (i < 216 && col < 216) {
      int h1 = i / 36, r1 = i - h1 * 36, w1 = r1 / 6, d1 = r1 - w1 * 6;
      int idx = ((h1 - h2 + 5) * 11 + (w1 - w2 + 5)) * 11 + (d1 - d2 + 5);
      val = pos[idx * 6 + h];
    }
    o[r] = f2bf(val);
  }
  *(ushort4_*)(out + (size_t)tgl * 4) = o;
}

// =====================================================================
// 2b) mask fragments: per group, MFMA C-layout, bf16
// =====================================================================
__global__ void maskfrag_kernel(const void* __restrict__ maskv,
                                const int* __restrict__ flag,
                                ushort* __restrict__ out) {
  int tgl = blockIdx.x * 256 + threadIdx.x;
  if (tgl >= 64 * 196 * 64) return;
  bool mf32 = flag[0] != 0;
  int lane = tgl & 63;
  int tj   = (tgl >> 6) % 196;
  int g    = (tgl >> 6) / 196;
  int tt = tj / 14, j = tj - tt * 14;
  int l16 = lane & 15, quad = lane >> 4;
  int col = j * 16 + l16;
  const float*  mf = (const float*)maskv + (size_t)g * NSQ;
  const ushort* mu = (const ushort*)maskv + (size_t)g * NSQ;
  ushort4_ o;
#pragma unroll
  for (int r = 0; r < 4; ++r) {
    int i = tt * 16 + quad * 4 + r;
    float val = PADV;
    if (i < 216 && col < 216) {
      int mi = i * 216 + col;
      val = mf32 ? mf[mi] : bf2f(mu[mi]);
    }
    o[r] = f2bf(val);
  }
  *(ushort4_*)(out + (size_t)tgl * 4) = o;
}

// =====================================================================
// 3) GEMM: M-tile 128, N-tile 192 (full), K=192 in 3 chunks of 64
//    qkv: z=0 -> q (scaled, from x), z=1 -> k, z=2 -> v (from y); (b,h,n,d)
//    proj: plain row-major out (fp32 or bf16 per flag)
// =====================================================================
__global__ __launch_bounds__(256) void gemm_kernel(
    const void* __restrict__ Ax, const void* __restrict__ Ay,
    const ushort* __restrict__ W,  const ushort* __restrict__ bias,
    void* __restrict__ dq, void* __restrict__ dk, void* __restrict__ dv,
    const int* __restrict__ flag, int is_proj) {
  __shared__ __align__(16) ushort a_lds[128 * 72];
  __shared__ __align__(16) ushort b_lds[192 * 72];
  int tid = threadIdx.x;
  int m0 = blockIdx.x * 128;
  int z  = blockIdx.z;
  const void* A = (z == 0) ? Ax : Ay;
  int wbase = is_proj ? 0 : z * 192;
  float scale = (!is_proj && z == 0) ? 0.17677669529663687f : 1.0f;
  void* dst = (z == 0) ? dq : (z == 1 ? dk : dv);
  bool a_f32 = (!is_proj) && (flag[0] != 0);
  bool o_f32 = is_proj && (flag[0] != 0);

  int lane = tid & 63, w = tid >> 6;
  int l16 = lane & 15, quad = lane >> 4;
  int wm = w >> 1, wn = w & 1;

  float4_ acc[4][6];
#pragma unroll
  for (int mt = 0; mt < 4; ++mt)
#pragma unroll
    for (int nt = 0; nt < 6; ++nt) acc[mt][nt] = (float4_){0.f, 0.f, 0.f, 0.f};

  for (int kc = 0; kc < 3; ++kc) {
    // stage A: 128 x 64
    for (int i = tid; i < 1024; i += 256) {
      int row = i >> 3, c8 = i & 7;
      short8 pk;
      if (a_f32) {
        const float* Af = (const float*)A + (size_t)(m0 + row) * 192 + kc * 64 + c8 * 8;
        float4_ lo = *(const float4_*)Af;
        float4_ hi = *(const float4_*)(Af + 4);
#pragma unroll
        for (int jj = 0; jj < 4; ++jj) {
          pk[jj]     = (short)f2bf(lo[jj]);
          pk[4 + jj] = (short)f2bf(hi[jj]);
        }
      } else {
        pk = *(const short8*)((const ushort*)A + (size_t)(m0 + row) * 192 + kc * 64 + c8 * 8);
      }
      *(short8*)(a_lds + row * 72 + c8 * 8) = pk;
    }
    // stage B: 192 x 64
    for (int i = tid; i < 1536; i += 256) {
      int row = i >> 3, c8 = i & 7;
      short8 pk = *(const short8*)(W + (size_t)(wbase + row) * 192 + kc * 64 + c8 * 8);
      *(short8*)(b_lds + row * 72 + c8 * 8) = pk;
    }
    __syncthreads();
#pragma unroll
    for (int kk = 0; kk < 2; ++kk) {
      short8 af[4], bfr[6];
#pragma unroll
      for (int mt = 0; mt < 4; ++mt)
        af[mt] = *(const short8*)(a_lds + (wm * 64 + mt * 16 + l16) * 72 + kk * 32 + quad * 8);
#pragma unroll
      for (int nt = 0; nt < 6; ++nt)
        bfr[nt] = *(const short8*)(b_lds + (wn * 96 + nt * 16 + l16) * 72 + kk * 32 + quad * 8);
#pragma unroll
      for (int mt = 0; mt < 4; ++mt)
#pragma unroll
        for (int nt = 0; nt < 6; ++nt)
          acc[mt][nt] = __builtin_amdgcn_mfma_f32_16x16x32_bf16(af[mt], bfr[nt], acc[mt][nt], 0, 0, 0);
    }
    __syncthreads();
  }

#pragma unroll
  for (int mt = 0; mt < 4; ++mt) {
#pragma unroll
    for (int nt = 0; nt < 6; ++nt) {
      int lcol = wn * 96 + nt * 16 + l16;   // 0..191
      float bv = bf2f(bias[(is_proj ? 0 : z * 192) + lcol]);
#pragma unroll
      for (int r = 0; r < 4; ++r) {
        int grow = m0 + wm * 64 + mt * 16 + quad * 4 + r;
        float val = (acc[mt][nt][r] + bv) * scale;
        if (is_proj) {
          if (o_f32) ((float*)dst)[(size_t)grow * 192 + lcol] = val;
          else       ((ushort*)dst)[(size_t)grow * 192 + lcol] = f2bf(val);
        } else {
          int bb = grow / 216;
          int nn2 = grow - bb * 216;
          int hh = lcol >> 5, dd = lcol & 31;
          ((ushort*)dst)[(((size_t)bb * 6 + hh) * 216 + nn2) * 32 + dd] = f2bf(val);
        }
      }
    }
  }
}

// =====================================================================
// 4) fused attention: one WG (4 waves) per (b, h); bias via fragments
// =====================================================================
__global__ __launch_bounds__(256) void attn_kernel(
    const ushort* __restrict__ q, const ushort* __restrict__ k,
    const ushort* __restrict__ v, const ushort* __restrict__ rpbf,
    const ushort* __restrict__ maskf, ushort* __restrict__ opre) {
  __shared__ __align__(16) ushort vts[32 * 232];     // v^T, padded cols
  __shared__ __align__(16) ushort ps[4][16 * 232];   // per-wave P tile

  int bid = blockIdx.x;
  int b = bid / 6, h = bid - b * 6;
  int g = b & 63;
  int tid = threadIdx.x, lane = tid & 63, w = tid >> 6;
  int l16 = lane & 15, quad = lane >> 4;

  const ushort* qh = q + (size_t)(b * 6 + h) * 6912;
  const ushort* kh = k + (size_t)(b * 6 + h) * 6912;
  const ushort* vh = v + (size_t)(b * 6 + h) * 6912;

  // zero vts (pad cols must be 0), then transpose v into it
  for (int i = tid; i < (32 * 232) / 2; i += 256) ((uint*)vts)[i] = 0u;
  __syncthreads();
  for (int i = tid; i < 864; i += 256) {
    int n = i >> 2, dp = (i & 3) * 8;
    uint4 raw = *(const uint4*)(vh + n * 32 + dp);
    const ushort* ep = reinterpret_cast<const ushort*>(&raw);
#pragma unroll
    for (int jj = 0; jj < 8; ++jj) vts[(dp + jj) * 232 + n] = ep[jj];
  }
  __syncthreads();

  for (int t = w; t < 14; t += 4) {
    int r0 = t * 16;
    const ushort* rf = rpbf  + ((size_t)(h * 196 + t * 14) * 64 + lane) * 4;
    const ushort* mf = maskf + ((size_t)(g * 196 + t * 14) * 64 + lane) * 4;
    short8 aq = *(const short8*)(qh + (r0 + l16) * 32 + quad * 8);

    float4_ s[14];
#pragma unroll
    for (int j = 0; j < 14; ++j) {
      ushort4_ rb = *(const ushort4_*)(rf + j * 256);
      ushort4_ mb = *(const ushort4_*)(mf + j * 256);
      float4_ cin;
#pragma unroll
      for (int r = 0; r < 4; ++r) cin[r] = bf2f(rb[r]) + bf2f(mb[r]);
      short8 bk = *(const short8*)(kh + (j * 16 + l16) * 32 + quad * 8);
      s[j] = __builtin_amdgcn_mfma_f32_16x16x32_bf16(aq, bk, cin, 0, 0, 0);
    }

#pragma unroll
    for (int r = 0; r < 4; ++r) {
      float mx = -1e30f;
#pragma unroll
      for (int j = 0; j < 14; ++j) mx = fmaxf(mx, s[j][r]);
      mx = fmaxf(mx, __shfl_xor(mx, 1));
      mx = fmaxf(mx, __shfl_xor(mx, 2));
      mx = fmaxf(mx, __shfl_xor(mx, 4));
      mx = fmaxf(mx, __shfl_xor(mx, 8));
      float sum = 0.f;
#pragma unroll
      for (int j = 0; j < 14; ++j) {
        float pe = __expf(s[j][r] - mx);
        s[j][r] = pe;
        sum += pe;
      }
      sum += __shfl_xor(sum, 1);
      sum += __shfl_xor(sum, 2);
      sum += __shfl_xor(sum, 4);
      sum += __shfl_xor(sum, 8);
      float inv = 1.0f / sum;
#pragma unroll
      for (int j = 0; j < 14; ++j)
        ps[w][(quad * 4 + r) * 232 + j * 16 + l16] = f2bf(s[j][r] * inv);
    }

    asm volatile("s_waitcnt lgkmcnt(0)" ::: "memory");

    float4_ o0 = (float4_){0.f, 0.f, 0.f, 0.f};
    float4_ o1 = (float4_){0.f, 0.f, 0.f, 0.f};
#pragma unroll
    for (int kt = 0; kt < 7; ++kt) {
      short8 pf = *(const short8*)(&ps[w][l16 * 232 + kt * 32 + quad * 8]);
      short8 v0 = *(const short8*)(&vts[(l16) * 232 + kt * 32 + quad * 8]);
      short8 v1 = *(const short8*)(&vts[(16 + l16) * 232 + kt * 32 + quad * 8]);
      o0 = __builtin_amdgcn_mfma_f32_16x16x32_bf16(pf, v0, o0, 0, 0, 0);
      o1 = __builtin_amdgcn_mfma_f32_16x16x32_bf16(pf, v1, o1, 0, 0, 0);
    }

#pragma unroll
    for (int r = 0; r < 4; ++r) {
      int i = r0 + quad * 4 + r;
      if (i < 216) {
        size_t base = ((size_t)b * 216 + i) * 192 + h * 32;
        opre[base + l16]      = f2bf(o0[r]);
        opre[base + 16 + l16] = f2bf(o1[r]);
      }
    }
  }
}

// =====================================================================
// launch
// =====================================================================
extern "C" void kernel_launch(void* const* d_in, const int* in_sizes, int n_in,
                              void* d_out, int out_size, void* d_ws, size_t ws_size,
                              hipStream_t stream) {
  (void)in_sizes; (void)n_in; (void)out_size; (void)ws_size;

  char* p = (char*)d_ws;
  int*    flag   = (int*)p;            p += 256;
  ushort* warena = (ushort*)p;         p += 298496 - 256;
  float*  pos    = (float*)p;          p += 32000;
  ushort* rpbf   = (ushort*)p;         p += 602112;    // 6*196*64*4*2
  ushort* maskf  = (ushort*)p;         p += 6422528;   // 64*196*64*4*2
  ushort* qb     = (ushort*)p;         p += 21234688;
  ushort* kb     = (ushort*)p;         p += 21234688;
  ushort* vb     = (ushort*)p;         p += 21234688;
  ushort* opre   = (ushort*)p;

  detect_kernel<<<1, 64, 0, stream>>>((const uint*)d_in[0], flag);

  SrcPtrs sp;
  for (int i = 0; i < 18; ++i) sp.p[i] = d_in[3 + i];
  convert_kernel<<<(WA_TOTAL + 255) / 256, 256, 0, stream>>>(sp, warena, flag);

  pos_mlp_kernel<<<6, 256, 0, stream>>>(warena, pos);
  rpbfrag_kernel<<<294, 256, 0, stream>>>(pos, rpbf);
  maskfrag_kernel<<<3136, 256, 0, stream>>>(d_in[2], flag, maskf);

  gemm_kernel<<<dim3(432, 1, 3), 256, 0, stream>>>(
      d_in[0], d_in[1], warena + WA_WQKV, warena + WA_BQKV,
      qb, kb, vb, flag, 0);

  attn_kernel<<<1536, 256, 0, stream>>>(qb, kb, vb, rpbf, maskf, opre);

  gemm_kernel<<<dim3(432, 1, 1), 256, 0, stream>>>(
      opre, opre, warena + WA_WPROJ, warena + WA_BPROJ,
      d_out, d_out, d_out, flag, 1);
}

// Round 4
// 322.028 us; speedup vs baseline: 1.2564x; 1.0446x over previous
//
#include <hip/hip_runtime.h>
#include <stdint.h>

using short8   = __attribute__((ext_vector_type(8))) short;
using float4_  = __attribute__((ext_vector_type(4))) float;
using ushort4_ = __attribute__((ext_vector_type(4))) unsigned short;
typedef unsigned int  uint;
typedef unsigned short ushort;

// ---------- bf16 helpers ----------
__device__ __forceinline__ float bf2f(ushort b) {
  uint u = ((uint)b) << 16;
  return __builtin_bit_cast(float, u);
}
__device__ __forceinline__ ushort f2bf(float f) {
  uint u = __builtin_bit_cast(uint, f);
  u = u + 0x7fffu + ((u >> 16) & 1u);   // RTNE
  return (ushort)(u >> 16);
}

// ---------- constants ----------
#define NN   216      // tokens (6*6*6)
#define NSQ  46656    // 216*216
#define PADV (-3.0e6f)

// weight arena element offsets
#define WA_WQKV   0
#define WA_BQKV   110592
#define WA_WPROJ  111168
#define WA_BPROJ  148032
#define WA_PPW    148224
#define WA_PPB    148260
#define WA_G1     148272
#define WA_B1     148284
#define WA_W1     148296
#define WA_WB1    148440
#define WA_G2     148452
#define WA_B2     148464
#define WA_W2     148476
#define WA_WB2    148620
#define WA_G3     148632
#define WA_B3     148644
#define WA_W3     148656
#define WA_WB3    148728
#define WA_TOTAL  148740

// =====================================================================
// 0) dtype detector: flag = 0 (bf16 inputs) / 1 (fp32 inputs)
// =====================================================================
__global__ void detect_kernel(const uint* __restrict__ x, int* __restrict__ flag) {
  int lane = threadIdx.x;
  uint w = x[lane];
  ushort lo = (ushort)(w & 0xffffu);
  int e = (lo >> 7) & 0xff;
  int sane = (lo == 0 || (e >= 0x60 && e <= 0x9f)) ? 1 : 0;
  unsigned long long b = __ballot(sane);
  if (lane == 0) flag[0] = (__popcll(b) >= 56) ? 0 : 1;
}

// =====================================================================
// 0b) weight conversion into canonical bf16 arena
// =====================================================================
struct SrcPtrs { const void* p[18]; };

__global__ void convert_kernel(SrcPtrs sp, ushort* __restrict__ dst,
                               const int* __restrict__ flag) {
  constexpr int OFF[19] = {WA_WQKV, WA_BQKV, WA_WPROJ, WA_BPROJ, WA_PPW, WA_PPB,
                           WA_G1, WA_B1, WA_W1, WA_WB1, WA_G2, WA_B2, WA_W2,
                           WA_WB2, WA_G3, WA_B3, WA_W3, WA_WB3, WA_TOTAL};
  int t = blockIdx.x * 256 + threadIdx.x;
  if (t >= WA_TOTAL) return;
  int a = 0;
#pragma unroll
  for (int i = 1; i < 18; ++i) a += (t >= OFF[i]) ? 1 : 0;
  int local = t - OFF[a];
  const void* s = sp.p[a];
  ushort v;
  if (flag[0]) v = f2bf(((const float*)s)[local]);
  else         v = ((const ushort*)s)[local];
  dst[t] = v;
}

// =====================================================================
// 0c) y fp32 -> bf16 streaming convert (no-op when inputs already bf16)
// =====================================================================
__global__ __launch_bounds__(256) void cvt_kernel(const float* __restrict__ src,
                                                  ushort* __restrict__ dst,
                                                  const int* __restrict__ flag) {
  if (flag[0] == 0) return;
  size_t s = ((size_t)blockIdx.x * 256 + threadIdx.x) * 8;
  float4_ lo = *(const float4_*)(src + s);
  float4_ hi = *(const float4_*)(src + s + 4);
  short8 pk;
#pragma unroll
  for (int j = 0; j < 4; ++j) {
    pk[j]     = (short)f2bf(lo[j]);
    pk[4 + j] = (short)f2bf(hi[j]);
  }
  *(short8*)(dst + s) = pk;
}

// =====================================================================
// 1) pos MLP: offsets (1331,3) -> pos (1331, 6)   [fp32 out]
// =====================================================================
__device__ __forceinline__ void ln_relu(const float* p, const ushort* g,
                                        const ushort* b, float* r) {
  float m = 0.f;
#pragma unroll
  for (int t = 0; t < 12; ++t) m += p[t];
  m *= (1.f / 12.f);
  float v = 0.f;
#pragma unroll
  for (int t = 0; t < 12; ++t) { float d = p[t] - m; v += d * d; }
  v *= (1.f / 12.f);
  float inv = rsqrtf(v + 1e-5f);
#pragma unroll
  for (int t = 0; t < 12; ++t) {
    float z = (p[t] - m) * inv * bf2f(g[t]) + bf2f(b[t]);
    r[t] = fmaxf(z, 0.f);
  }
}

__global__ void pos_mlp_kernel(const ushort* __restrict__ wa, float* __restrict__ pos) {
  int m = blockIdx.x * blockDim.x + threadIdx.x;
  if (m >= 1331) return;
  const ushort* pw  = wa + WA_PPW;  const ushort* pb  = wa + WA_PPB;
  const ushort* g1  = wa + WA_G1;   const ushort* b1  = wa + WA_B1;
  const ushort* w1  = wa + WA_W1;   const ushort* wb1 = wa + WA_WB1;
  const ushort* g2  = wa + WA_G2;   const ushort* b2  = wa + WA_B2;
  const ushort* w2  = wa + WA_W2;   const ushort* wb2 = wa + WA_WB2;
  const ushort* g3  = wa + WA_G3;   const ushort* b3  = wa + WA_B3;
  const ushort* w3  = wa + WA_W3;   const ushort* wb3 = wa + WA_WB3;

  int ih = m / 121, rem = m - ih * 121;
  int iw = rem / 11, id = rem - iw * 11;
  float fh = (float)(ih - 5), fw = (float)(iw - 5), fd = (float)(id - 5);
  float p[12], r[12], q[12];
#pragma unroll
  for (int t = 0; t < 12; ++t)
    p[t] = fh * bf2f(pw[t * 3]) + fw * bf2f(pw[t * 3 + 1]) +
           fd * bf2f(pw[t * 3 + 2]) + bf2f(pb[t]);
  ln_relu(p, g1, b1, r);
#pragma unroll
  for (int t = 0; t < 12; ++t) {
    float s = bf2f(wb1[t]);
#pragma unroll
    for (int u = 0; u < 12; ++u) s += r[u] * bf2f(w1[t * 12 + u]);
    q[t] = s;
  }
  ln_relu(q, g2, b2, r);
#pragma unroll
  for (int t = 0; t < 12; ++t) {
    float s = bf2f(wb2[t]);
#pragma unroll
    for (int u = 0; u < 12; ++u) s += r[u] * bf2f(w2[t * 12 + u]);
    p[t] = s;
  }
  ln_relu(p, g3, b3, r);
#pragma unroll
  for (int h = 0; h < 6; ++h) {
    float s = bf2f(wb3[h]);
#pragma unroll
    for (int u = 0; u < 12; ++u) s += r[u] * bf2f(w3[h * 12 + u]);
    pos[m * 6 + h] = s;
  }
}

// =====================================================================
// 2a) rpb fragments: per head, MFMA C-layout, bf16
// =====================================================================
__global__ void rpbfrag_kernel(const float* __restrict__ pos, ushort* __restrict__ out) {
  int tgl = blockIdx.x * 256 + threadIdx.x;
  if (tgl >= 6 * 196 * 64) return;
  int lane = tgl & 63;
  int tj   = (tgl >> 6) % 196;
  int h    = (tgl >> 6) / 196;
  int tt = tj / 14, j = tj - tt * 14;
  int l16 = lane & 15, quad = lane >> 4;
  int col = j * 16 + l16;
  int h2 = col / 36, r2 = col - h2 * 36, w2 = r2 / 6, d2 = r2 - w2 * 6;
  ushort4_ o;
#pragma unroll
  for (int r = 0; r < 4; ++r) {
    int i = tt * 16 + quad * 4 + r;
    float val = PADV;
    if (i < 216 && col < 216) {
      int h1 = i / 36, r1 = i - h1 * 36, w1 = r1 / 6, d1 = r1 - w1 * 6;
      int idx = ((h1 - h2 + 5) * 11 + (w1 - w2 + 5)) * 11 + (d1 - d2 + 5);
      val = pos[idx * 6 + h];
    }
    o[r] = f2bf(val);
  }
  *(ushort4_*)(out + (size_t)tgl * 4) = o;
}

// =====================================================================
// 2b) mask fragments: per group, MFMA C-layout, bf16
// =====================================================================
__global__ void maskfrag_kernel(const void* __restrict__ maskv,
                                const int* __restrict__ flag,
                                ushort* __restrict__ out) {
  int tgl = blockIdx.x * 256 + threadIdx.x;
  if (tgl >= 64 * 196 * 64) return;
  bool mf32 = flag[0] != 0;
  int lane = tgl & 63;
  int tj   = (tgl >> 6) % 196;
  int g    = (tgl >> 6) / 196;
  int tt = tj / 14, j = tj - tt * 14;
  int l16 = lane & 15, quad = lane >> 4;
  int col = j * 16 + l16;
  const float*  mf = (const float*)maskv + (size_t)g * NSQ;
  const ushort* mu = (const ushort*)maskv + (size_t)g * NSQ;
  ushort4_ o;
#pragma unroll
  for (int r = 0; r < 4; ++r) {
    int i = tt * 16 + quad * 4 + r;
    float val = PADV;
    if (i < 216 && col < 216) {
      int mi = i * 216 + col;
      val = mf32 ? mf[mi] : bf2f(mu[mi]);
    }
    o[r] = f2bf(val);
  }
  *(ushort4_*)(out + (size_t)tgl * 4) = o;
}

// =====================================================================
// 3) GEMM: M-tile 128 (4 waves x 32 rows), N-tile 96, K = 192 (no chunking)
//    B (weights) staged once into LDS in MFMA-fragment-linear order;
//    A fragments read directly from global. One barrier per block.
//    qkv: z=0 -> q from x (scaled), z=1 -> k, z=2 -> v from y; (b,h,n,d)
//    proj: plain row-major out (fp32 or bf16 per flag)
// =====================================================================
__global__ __launch_bounds__(256) void gemm_kernel(
    const void* __restrict__ p0,          // x (orig dtype)   [qkv z=0]
    const ushort* __restrict__ p1,        // ycvt (qkv) / opre (proj)
    const void* __restrict__ p2,          // y (orig dtype)   [qkv z=1,2 bf16 case]
    const ushort* __restrict__ W,  const ushort* __restrict__ bias,
    void* __restrict__ dq, void* __restrict__ dk, void* __restrict__ dv,
    const int* __restrict__ flag, int is_proj) {
  __shared__ __align__(16) ushort b_lds[2304 * 8];   // 36,864 B

  int tid = threadIdx.x;
  int m0 = blockIdx.x * 128;
  int n0 = blockIdx.y * 96;
  int z  = blockIdx.z;
  int wbase = is_proj ? 0 : z * 192;
  float scale = (!is_proj && z == 0) ? 0.17677669529663687f : 1.0f;
  void* dst = (z == 0) ? dq : (z == 1 ? dk : dv);
  int fl = flag[0];
  bool f32path = (!is_proj) && (z == 0) && (fl != 0);
  bool o_f32 = is_proj && (fl != 0);

  const ushort* A16;
  if (is_proj)      A16 = p1;
  else if (z == 0)  A16 = (const ushort*)p0;       // only used when fl==0
  else              A16 = fl ? p1 : (const ushort*)p2;
  const float* A32 = (const float*)p0;

  int lane = tid & 63, w = tid >> 6;
  int l16 = lane & 15, quad = lane >> 4;

  // ---- stage B: 96 cols x 192 k, fragment-linear ----
  for (int s = tid; s < 2304; s += 256) {
    int kk = s / 384;
    int rem = s - kk * 384;
    int nt = rem >> 6;
    int l  = rem & 63;
    int l16v = l & 15, qv = l >> 4;
    short8 pk = *(const short8*)(W + (size_t)(wbase + n0 + nt * 16 + l16v) * 192 + kk * 32 + qv * 8);
    *(short8*)(b_lds + s * 8) = pk;
  }
  __syncthreads();

  float4_ acc[2][6];
#pragma unroll
  for (int mt = 0; mt < 2; ++mt)
#pragma unroll
    for (int nt = 0; nt < 6; ++nt) acc[mt][nt] = (float4_){0.f, 0.f, 0.f, 0.f};

#pragma unroll
  for (int kk = 0; kk < 6; ++kk) {
    short8 af[2];
#pragma unroll
    for (int mt = 0; mt < 2; ++mt) {
      size_t abase = (size_t)(m0 + w * 32 + mt * 16 + l16) * 192 + kk * 32 + quad * 8;
      if (f32path) {
        float4_ lo = *(const float4_*)(A32 + abase);
        float4_ hi = *(const float4_*)(A32 + abase + 4);
#pragma unroll
        for (int j = 0; j < 4; ++j) {
          af[mt][j]     = (short)f2bf(lo[j]);
          af[mt][4 + j] = (short)f2bf(hi[j]);
        }
      } else {
        af[mt] = *(const short8*)(A16 + abase);
      }
    }
    short8 bfr[6];
#pragma unroll
    for (int nt = 0; nt < 6; ++nt)
      bfr[nt] = *(const short8*)(b_lds + ((kk * 6 + nt) * 64 + lane) * 8);
#pragma unroll
    for (int mt = 0; mt < 2; ++mt)
#pragma unroll
      for (int nt = 0; nt < 6; ++nt)
        acc[mt][nt] = __builtin_amdgcn_mfma_f32_16x16x32_bf16(af[mt], bfr[nt], acc[mt][nt], 0, 0, 0);
  }

#pragma unroll
  for (int mt = 0; mt < 2; ++mt) {
#pragma unroll
    for (int nt = 0; nt < 6; ++nt) {
      int lcol = n0 + nt * 16 + l16;   // 0..191
      float bv = bf2f(bias[(is_proj ? 0 : z * 192) + lcol]);
#pragma unroll
      for (int r = 0; r < 4; ++r) {
        int grow = m0 + w * 32 + mt * 16 + quad * 4 + r;
        float val = (acc[mt][nt][r] + bv) * scale;
        if (is_proj) {
          if (o_f32) ((float*)dst)[(size_t)grow * 192 + lcol] = val;
          else       ((ushort*)dst)[(size_t)grow * 192 + lcol] = f2bf(val);
        } else {
          int bb = grow / 216;
          int nn2 = grow - bb * 216;
          int hh = lcol >> 5, dd = lcol & 31;
          ((ushort*)dst)[(((size_t)bb * 6 + hh) * 216 + nn2) * 32 + dd] = f2bf(val);
        }
      }
    }
  }
}

// =====================================================================
// 4) fused attention: one WG (4 waves) per (b, h); bias via fragments
// =====================================================================
__global__ __launch_bounds__(256) void attn_kernel(
    const ushort* __restrict__ q, const ushort* __restrict__ k,
    const ushort* __restrict__ v, const ushort* __restrict__ rpbf,
    const ushort* __restrict__ maskf, ushort* __restrict__ opre) {
  __shared__ __align__(16) ushort vts[32 * 232];     // v^T, padded cols
  __shared__ __align__(16) ushort ps[4][16 * 232];   // per-wave P tile

  int bid = blockIdx.x;
  int b = bid / 6, h = bid - b * 6;
  int g = b & 63;
  int tid = threadIdx.x, lane = tid & 63, w = tid >> 6;
  int l16 = lane & 15, quad = lane >> 4;

  const ushort* qh = q + (size_t)(b * 6 + h) * 6912;
  const ushort* kh = k + (size_t)(b * 6 + h) * 6912;
  const ushort* vh = v + (size_t)(b * 6 + h) * 6912;

  for (int i = tid; i < (32 * 232) / 2; i += 256) ((uint*)vts)[i] = 0u;
  __syncthreads();
  for (int i = tid; i < 864; i += 256) {
    int n = i >> 2, dp = (i & 3) * 8;
    uint4 raw = *(const uint4*)(vh + n * 32 + dp);
    const ushort* ep = reinterpret_cast<const ushort*>(&raw);
#pragma unroll
    for (int jj = 0; jj < 8; ++jj) vts[(dp + jj) * 232 + n] = ep[jj];
  }
  __syncthreads();

  for (int t = w; t < 14; t += 4) {
    int r0 = t * 16;
    const ushort* rf = rpbf  + ((size_t)(h * 196 + t * 14) * 64 + lane) * 4;
    const ushort* mf = maskf + ((size_t)(g * 196 + t * 14) * 64 + lane) * 4;
    short8 aq = *(const short8*)(qh + (r0 + l16) * 32 + quad * 8);

    float4_ s[14];
#pragma unroll
    for (int j = 0; j < 14; ++j) {
      ushort4_ rb = *(const ushort4_*)(rf + j * 256);
      ushort4_ mb = *(const ushort4_*)(mf + j * 256);
      float4_ cin;
#pragma unroll
      for (int r = 0; r < 4; ++r) cin[r] = bf2f(rb[r]) + bf2f(mb[r]);
      short8 bk = *(const short8*)(kh + (j * 16 + l16) * 32 + quad * 8);
      s[j] = __builtin_amdgcn_mfma_f32_16x16x32_bf16(aq, bk, cin, 0, 0, 0);
    }

#pragma unroll
    for (int r = 0; r < 4; ++r) {
      float mx = -1e30f;
#pragma unroll
      for (int j = 0; j < 14; ++j) mx = fmaxf(mx, s[j][r]);
      mx = fmaxf(mx, __shfl_xor(mx, 1));
      mx = fmaxf(mx, __shfl_xor(mx, 2));
      mx = fmaxf(mx, __shfl_xor(mx, 4));
      mx = fmaxf(mx, __shfl_xor(mx, 8));
      float sum = 0.f;
#pragma unroll
      for (int j = 0; j < 14; ++j) {
        float pe = __expf(s[j][r] - mx);
        s[j][r] = pe;
        sum += pe;
      }
      sum += __shfl_xor(sum, 1);
      sum += __shfl_xor(sum, 2);
      sum += __shfl_xor(sum, 4);
      sum += __shfl_xor(sum, 8);
      float inv = 1.0f / sum;
#pragma unroll
      for (int j = 0; j < 14; ++j)
        ps[w][(quad * 4 + r) * 232 + j * 16 + l16] = f2bf(s[j][r] * inv);
    }

    asm volatile("s_waitcnt lgkmcnt(0)" ::: "memory");

    float4_ o0 = (float4_){0.f, 0.f, 0.f, 0.f};
    float4_ o1 = (float4_){0.f, 0.f, 0.f, 0.f};
#pragma unroll
    for (int kt = 0; kt < 7; ++kt) {
      short8 pf = *(const short8*)(&ps[w][l16 * 232 + kt * 32 + quad * 8]);
      short8 v0 = *(const short8*)(&vts[(l16) * 232 + kt * 32 + quad * 8]);
      short8 v1 = *(const short8*)(&vts[(16 + l16) * 232 + kt * 32 + quad * 8]);
      o0 = __builtin_amdgcn_mfma_f32_16x16x32_bf16(pf, v0, o0, 0, 0, 0);
      o1 = __builtin_amdgcn_mfma_f32_16x16x32_bf16(pf, v1, o1, 0, 0, 0);
    }

#pragma unroll
    for (int r = 0; r < 4; ++r) {
      int i = r0 + quad * 4 + r;
      if (i < 216) {
        size_t base = ((size_t)b * 216 + i) * 192 + h * 32;
        opre[base + l16]      = f2bf(o0[r]);
        opre[base + 16 + l16] = f2bf(o1[r]);
      }
    }
  }
}

// =====================================================================
// launch
// =====================================================================
extern "C" void kernel_launch(void* const* d_in, const int* in_sizes, int n_in,
                              void* d_out, int out_size, void* d_ws, size_t ws_size,
                              hipStream_t stream) {
  (void)in_sizes; (void)n_in; (void)out_size; (void)ws_size;

  char* p = (char*)d_ws;
  int*    flag   = (int*)p;            p += 256;
  ushort* warena = (ushort*)p;         p += 298240;
  float*  pos    = (float*)p;          p += 32768;
  ushort* rpbf   = (ushort*)p;         p += 602112;    // 6*196*64*4*2
  ushort* maskf  = (ushort*)p;         p += 6422528;   // 64*196*64*4*2
  ushort* ycvt   = (ushort*)p;         p += 21234688;  // aliased as opre after QKV GEMM
  ushort* qb     = (ushort*)p;         p += 21234688;
  ushort* kb     = (ushort*)p;         p += 21234688;
  ushort* vb     = (ushort*)p;
  ushort* opre   = ycvt;               // ycvt dead once qkv gemm retires

  detect_kernel<<<1, 64, 0, stream>>>((const uint*)d_in[0], flag);

  SrcPtrs sp;
  for (int i = 0; i < 18; ++i) sp.p[i] = d_in[3 + i];
  convert_kernel<<<(WA_TOTAL + 255) / 256, 256, 0, stream>>>(sp, warena, flag);

  cvt_kernel<<<5184, 256, 0, stream>>>((const float*)d_in[1], ycvt, flag);

  pos_mlp_kernel<<<6, 256, 0, stream>>>(warena, pos);
  rpbfrag_kernel<<<294, 256, 0, stream>>>(pos, rpbf);
  maskfrag_kernel<<<3136, 256, 0, stream>>>(d_in[2], flag, maskf);

  gemm_kernel<<<dim3(432, 2, 3), 256, 0, stream>>>(
      d_in[0], ycvt, d_in[1], warena + WA_WQKV, warena + WA_BQKV,
      qb, kb, vb, flag, 0);

  attn_kernel<<<1536, 256, 0, stream>>>(qb, kb, vb, rpbf, maskf, opre);

  gemm_kernel<<<dim3(432, 2, 1), 256, 0, stream>>>(
      opre, opre, opre, warena + WA_WPROJ, warena + WA_BPROJ,
      d_out, d_out, d_out, flag, 1);
}

// Round 5
// 303.272 us; speedup vs baseline: 1.3341x; 1.0618x over previous
//
#include <hip/hip_runtime.h>
#include <stdint.h>

using short8   = __attribute__((ext_vector_type(8))) short;
using short4_  = __attribute__((ext_vector_type(4))) short;
using float4_  = __attribute__((ext_vector_type(4))) float;
using ushort4_ = __attribute__((ext_vector_type(4))) unsigned short;
typedef unsigned int  uint;
typedef unsigned short ushort;

// ---------- bf16 helpers ----------
__device__ __forceinline__ float bf2f(ushort b) {
  uint u = ((uint)b) << 16;
  return __builtin_bit_cast(float, u);
}
__device__ __forceinline__ ushort f2bf(float f) {
  uint u = __builtin_bit_cast(uint, f);
  u = u + 0x7fffu + ((u >> 16) & 1u);   // RTNE
  return (ushort)(u >> 16);
}

// ---------- constants ----------
#define NN   216      // tokens (6*6*6)
#define NSQ  46656    // 216*216
#define PADV (-3.0e6f)

// 16x16x16 bf16 MFMA selection
#if __has_builtin(__builtin_amdgcn_mfma_f32_16x16x16bf16_1k)
  #define HAVE_MFMA16 1
  #define MFMA16(a, b, c) __builtin_amdgcn_mfma_f32_16x16x16bf16_1k(a, b, c, 0, 0, 0)
#elif __has_builtin(__builtin_amdgcn_mfma_f32_16x16x16_bf16)
  #define HAVE_MFMA16 1
  #define MFMA16(a, b, c) __builtin_amdgcn_mfma_f32_16x16x16_bf16(a, b, c, 0, 0, 0)
#else
  #define HAVE_MFMA16 0
#endif

// weight arena element offsets
#define WA_WQKV   0
#define WA_BQKV   110592
#define WA_WPROJ  111168
#define WA_BPROJ  148032
#define WA_PPW    148224
#define WA_PPB    148260
#define WA_G1     148272
#define WA_B1     148284
#define WA_W1     148296
#define WA_WB1    148440
#define WA_G2     148452
#define WA_B2     148464
#define WA_W2     148476
#define WA_WB2    148620
#define WA_G3     148632
#define WA_B3     148644
#define WA_W3     148656
#define WA_WB3    148728
#define WA_TOTAL  148740

// =====================================================================
// 0) dtype detector: flag = 0 (bf16 inputs) / 1 (fp32 inputs)
// =====================================================================
__global__ void detect_kernel(const uint* __restrict__ x, int* __restrict__ flag) {
  int lane = threadIdx.x;
  uint w = x[lane];
  ushort lo = (ushort)(w & 0xffffu);
  int e = (lo >> 7) & 0xff;
  int sane = (lo == 0 || (e >= 0x60 && e <= 0x9f)) ? 1 : 0;
  unsigned long long b = __ballot(sane);
  if (lane == 0) flag[0] = (__popcll(b) >= 56) ? 0 : 1;
}

// =====================================================================
// 0b) weight conversion into canonical bf16 arena
// =====================================================================
struct SrcPtrs { const void* p[18]; };

__global__ void convert_kernel(SrcPtrs sp, ushort* __restrict__ dst,
                               const int* __restrict__ flag) {
  constexpr int OFF[19] = {WA_WQKV, WA_BQKV, WA_WPROJ, WA_BPROJ, WA_PPW, WA_PPB,
                           WA_G1, WA_B1, WA_W1, WA_WB1, WA_G2, WA_B2, WA_W2,
                           WA_WB2, WA_G3, WA_B3, WA_W3, WA_WB3, WA_TOTAL};
  int t = blockIdx.x * 256 + threadIdx.x;
  if (t >= WA_TOTAL) return;
  int a = 0;
#pragma unroll
  for (int i = 1; i < 18; ++i) a += (t >= OFF[i]) ? 1 : 0;
  int local = t - OFF[a];
  const void* s = sp.p[a];
  ushort v;
  if (flag[0]) v = f2bf(((const float*)s)[local]);
  else         v = ((const ushort*)s)[local];
  dst[t] = v;
}

// =====================================================================
// 0c) y fp32 -> bf16 streaming convert (no-op when inputs already bf16)
// =====================================================================
__global__ __launch_bounds__(256) void cvt_kernel(const float* __restrict__ src,
                                                  ushort* __restrict__ dst,
                                                  const int* __restrict__ flag) {
  if (flag[0] == 0) return;
  size_t s = ((size_t)blockIdx.x * 256 + threadIdx.x) * 8;
  float4_ lo = *(const float4_*)(src + s);
  float4_ hi = *(const float4_*)(src + s + 4);
  short8 pk;
#pragma unroll
  for (int j = 0; j < 4; ++j) {
    pk[j]     = (short)f2bf(lo[j]);
    pk[4 + j] = (short)f2bf(hi[j]);
  }
  *(short8*)(dst + s) = pk;
}

// =====================================================================
// 1) pos MLP: offsets (1331,3) -> pos (1331, 6)   [fp32 out]
// =====================================================================
__device__ __forceinline__ void ln_relu(const float* p, const ushort* g,
                                        const ushort* b, float* r) {
  float m = 0.f;
#pragma unroll
  for (int t = 0; t < 12; ++t) m += p[t];
  m *= (1.f / 12.f);
  float v = 0.f;
#pragma unroll
  for (int t = 0; t < 12; ++t) { float d = p[t] - m; v += d * d; }
  v *= (1.f / 12.f);
  float inv = rsqrtf(v + 1e-5f);
#pragma unroll
  for (int t = 0; t < 12; ++t) {
    float z = (p[t] - m) * inv * bf2f(g[t]) + bf2f(b[t]);
    r[t] = fmaxf(z, 0.f);
  }
}

__global__ void pos_mlp_kernel(const ushort* __restrict__ wa, float* __restrict__ pos) {
  int m = blockIdx.x * blockDim.x + threadIdx.x;
  if (m >= 1331) return;
  const ushort* pw  = wa + WA_PPW;  const ushort* pb  = wa + WA_PPB;
  const ushort* g1  = wa + WA_G1;   const ushort* b1  = wa + WA_B1;
  const ushort* w1  = wa + WA_W1;   const ushort* wb1 = wa + WA_WB1;
  const ushort* g2  = wa + WA_G2;   const ushort* b2  = wa + WA_B2;
  const ushort* w2  = wa + WA_W2;   const ushort* wb2 = wa + WA_WB2;
  const ushort* g3  = wa + WA_G3;   const ushort* b3  = wa + WA_B3;
  const ushort* w3  = wa + WA_W3;   const ushort* wb3 = wa + WA_WB3;

  int ih = m / 121, rem = m - ih * 121;
  int iw = rem / 11, id = rem - iw * 11;
  float fh = (float)(ih - 5), fw = (float)(iw - 5), fd = (float)(id - 5);
  float p[12], r[12], q[12];
#pragma unroll
  for (int t = 0; t < 12; ++t)
    p[t] = fh * bf2f(pw[t * 3]) + fw * bf2f(pw[t * 3 + 1]) +
           fd * bf2f(pw[t * 3 + 2]) + bf2f(pb[t]);
  ln_relu(p, g1, b1, r);
#pragma unroll
  for (int t = 0; t < 12; ++t) {
    float s = bf2f(wb1[t]);
#pragma unroll
    for (int u = 0; u < 12; ++u) s += r[u] * bf2f(w1[t * 12 + u]);
    q[t] = s;
  }
  ln_relu(q, g2, b2, r);
#pragma unroll
  for (int t = 0; t < 12; ++t) {
    float s = bf2f(wb2[t]);
#pragma unroll
    for (int u = 0; u < 12; ++u) s += r[u] * bf2f(w2[t * 12 + u]);
    p[t] = s;
  }
  ln_relu(p, g3, b3, r);
#pragma unroll
  for (int h = 0; h < 6; ++h) {
    float s = bf2f(wb3[h]);
#pragma unroll
    for (int u = 0; u < 12; ++u) s += r[u] * bf2f(w3[h * 12 + u]);
    pos[m * 6 + h] = s;
  }
}

// =====================================================================
// 2a) rpb fragments, TRANSPOSED (S^T) MFMA C-layout, bf16
//     frag r-value = bias[i = tt*16 + (lane&15)][j = jt*16 + (lane>>4)*4 + r]
//     elem index = ((h*196 + tt*14 + jt)*64 + lane)*4 + r
// =====================================================================
__global__ void rpbfrag_kernel(const float* __restrict__ pos, ushort* __restrict__ out) {
  int tgl = blockIdx.x * 256 + threadIdx.x;
  if (tgl >= 6 * 196 * 64) return;
  int lane = tgl & 63;
  int tj   = (tgl >> 6) % 196;
  int h    = (tgl >> 6) / 196;
  int tt = tj / 14, jt = tj - tt * 14;
  int l16 = lane & 15, quad = lane >> 4;
  int i = tt * 16 + l16;
  int jbase = jt * 16 + quad * 4;
  ushort4_ o;
  if (i < 216 && jbase < 216) {
    int h1 = i / 36, r1 = i - h1 * 36, w1 = r1 / 6, d1 = r1 - w1 * 6;
#pragma unroll
    for (int r = 0; r < 4; ++r) {
      int j = jbase + r;
      int h2 = j / 36, r2 = j - h2 * 36, w2 = r2 / 6, d2 = r2 - w2 * 6;
      int idx = ((h1 - h2 + 5) * 11 + (w1 - w2 + 5)) * 11 + (d1 - d2 + 5);
      o[r] = f2bf(pos[idx * 6 + h]);
    }
  } else {
#pragma unroll
    for (int r = 0; r < 4; ++r) o[r] = f2bf(PADV);
  }
  *(ushort4_*)(out + (size_t)tgl * 4) = o;
}

// =====================================================================
// 2b) mask fragments, TRANSPOSED layout — contiguous float4 loads
// =====================================================================
__global__ void maskfrag_kernel(const void* __restrict__ maskv,
                                const int* __restrict__ flag,
                                ushort* __restrict__ out) {
  int tgl = blockIdx.x * 256 + threadIdx.x;
  if (tgl >= 64 * 196 * 64) return;
  bool mf32 = flag[0] != 0;
  int lane = tgl & 63;
  int tj   = (tgl >> 6) % 196;
  int g    = (tgl >> 6) / 196;
  int tt = tj / 14, jt = tj - tt * 14;
  int l16 = lane & 15, quad = lane >> 4;
  int i = tt * 16 + l16;
  int jbase = jt * 16 + quad * 4;
  ushort4_ o;
  if (i < 216 && jbase < 216) {
    int mi = i * 216 + jbase;
    if (mf32) {
      float4_ mv = *(const float4_*)((const float*)maskv + (size_t)g * NSQ + mi);
#pragma unroll
      for (int r = 0; r < 4; ++r) o[r] = f2bf(mv[r]);
    } else {
      o = *(const ushort4_*)((const ushort*)maskv + (size_t)g * NSQ + mi);
    }
  } else {
#pragma unroll
    for (int r = 0; r < 4; ++r) o[r] = f2bf(PADV);
  }
  *(ushort4_*)(out + (size_t)tgl * 4) = o;
}

// =====================================================================
// 3) GEMM: M-tile 128 (4 waves x 32 rows), N-tile 96, K = 192
// =====================================================================
__global__ __launch_bounds__(256) void gemm_kernel(
    const void* __restrict__ p0,
    const ushort* __restrict__ p1,
    const void* __restrict__ p2,
    const ushort* __restrict__ W,  const ushort* __restrict__ bias,
    void* __restrict__ dq, void* __restrict__ dk, void* __restrict__ dv,
    const int* __restrict__ flag, int is_proj) {
  __shared__ __align__(16) ushort b_lds[2304 * 8];

  int tid = threadIdx.x;
  int m0 = blockIdx.x * 128;
  int n0 = blockIdx.y * 96;
  int z  = blockIdx.z;
  int wbase = is_proj ? 0 : z * 192;
  float scale = (!is_proj && z == 0) ? 0.17677669529663687f : 1.0f;
  void* dst = (z == 0) ? dq : (z == 1 ? dk : dv);
  int fl = flag[0];
  bool f32path = (!is_proj) && (z == 0) && (fl != 0);
  bool o_f32 = is_proj && (fl != 0);

  const ushort* A16;
  if (is_proj)      A16 = p1;
  else if (z == 0)  A16 = (const ushort*)p0;
  else              A16 = fl ? p1 : (const ushort*)p2;
  const float* A32 = (const float*)p0;

  int lane = tid & 63, w = tid >> 6;
  int l16 = lane & 15, quad = lane >> 4;

  for (int s = tid; s < 2304; s += 256) {
    int kk = s / 384;
    int rem = s - kk * 384;
    int nt = rem >> 6;
    int l  = rem & 63;
    int l16v = l & 15, qv = l >> 4;
    short8 pk = *(const short8*)(W + (size_t)(wbase + n0 + nt * 16 + l16v) * 192 + kk * 32 + qv * 8);
    *(short8*)(b_lds + s * 8) = pk;
  }
  __syncthreads();

  float4_ acc[2][6];
#pragma unroll
  for (int mt = 0; mt < 2; ++mt)
#pragma unroll
    for (int nt = 0; nt < 6; ++nt) acc[mt][nt] = (float4_){0.f, 0.f, 0.f, 0.f};

#pragma unroll
  for (int kk = 0; kk < 6; ++kk) {
    short8 af[2];
#pragma unroll
    for (int mt = 0; mt < 2; ++mt) {
      size_t abase = (size_t)(m0 + w * 32 + mt * 16 + l16) * 192 + kk * 32 + quad * 8;
      if (f32path) {
        float4_ lo = *(const float4_*)(A32 + abase);
        float4_ hi = *(const float4_*)(A32 + abase + 4);
#pragma unroll
        for (int j = 0; j < 4; ++j) {
          af[mt][j]     = (short)f2bf(lo[j]);
          af[mt][4 + j] = (short)f2bf(hi[j]);
        }
      } else {
        af[mt] = *(const short8*)(A16 + abase);
      }
    }
    short8 bfr[6];
#pragma unroll
    for (int nt = 0; nt < 6; ++nt)
      bfr[nt] = *(const short8*)(b_lds + ((kk * 6 + nt) * 64 + lane) * 8);
#pragma unroll
    for (int mt = 0; mt < 2; ++mt)
#pragma unroll
      for (int nt = 0; nt < 6; ++nt)
        acc[mt][nt] = __builtin_amdgcn_mfma_f32_16x16x32_bf16(af[mt], bfr[nt], acc[mt][nt], 0, 0, 0);
  }

#pragma unroll
  for (int mt = 0; mt < 2; ++mt) {
#pragma unroll
    for (int nt = 0; nt < 6; ++nt) {
      int lcol = n0 + nt * 16 + l16;
      float bv = bf2f(bias[(is_proj ? 0 : z * 192) + lcol]);
#pragma unroll
      for (int r = 0; r < 4; ++r) {
        int grow = m0 + w * 32 + mt * 16 + quad * 4 + r;
        float val = (acc[mt][nt][r] + bv) * scale;
        if (is_proj) {
          if (o_f32) ((float*)dst)[(size_t)grow * 192 + lcol] = val;
          else       ((ushort*)dst)[(size_t)grow * 192 + lcol] = f2bf(val);
        } else {
          int bb = grow / 216;
          int nn2 = grow - bb * 216;
          int hh = lcol >> 5, dd = lcol & 31;
          ((ushort*)dst)[(((size_t)bb * 6 + hh) * 216 + nn2) * 32 + dd] = f2bf(val);
        }
      }
    }
  }
}

// =====================================================================
// 4) fused attention v2 (S^T trick): one WG (4 waves) per (b, h)
//    S^T = mfma32(A=k, B=q, cin^T)  ->  C-frag IS the PV A-frag (x16)
//    P never touches LDS; V staged in B-frag-linear LDS.
// =====================================================================
__global__ __launch_bounds__(256) void attn_kernel(
    const ushort* __restrict__ q, const ushort* __restrict__ k,
    const ushort* __restrict__ v, const ushort* __restrict__ rpbf,
    const ushort* __restrict__ maskf, ushort* __restrict__ opre) {
#if HAVE_MFMA16
  __shared__ __align__(16) ushort vfrag[28 * 64 * 4];   // 14336 B, x16 B-frags
#else
  __shared__ __align__(16) ushort vfrag[14 * 64 * 8];   // 14336 B, x32 B-frags
#endif

  int bid = blockIdx.x;
  int b = bid / 6, h = bid - b * 6;
  int g = b & 63;
  int tid = threadIdx.x, lane = tid & 63, w = tid >> 6;
  int l16 = lane & 15, quad = lane >> 4;

  const ushort* qh = q + (size_t)(b * 6 + h) * 6912;
  const ushort* kh = k + (size_t)(b * 6 + h) * 6912;
  const ushort* vh = v + (size_t)(b * 6 + h) * 6912;

  // ---- stage V into B-fragment-linear LDS ----
#if HAVE_MFMA16
  // chunk = kt*2+dh (kt 0..13, dh 0..1); elem (lane, j) = V[kt*16+(l>>4)*4+j][dh*16+(l&15)]
  for (int pos = tid; pos < 1792; pos += 256) {
    int chunk = pos >> 6, l = pos & 63;
    int kt = chunk >> 1, dh = chunk & 1;
    int qd = l >> 4, lv = l & 15;
    ushort4_ tmp;
#pragma unroll
    for (int j = 0; j < 4; ++j)
      tmp[j] = vh[(kt * 16 + qd * 4 + j) * 32 + dh * 16 + lv];
    *(ushort4_*)(vfrag + pos * 4) = tmp;
  }
#else
  // chunk = kt2*2+dh (kt2 0..6, dh 0..1); elem (lane, j) = V[kt2*32+(l>>4)*8+j][dh*16+(l&15)]
  for (int pos = tid; pos < 896; pos += 256) {
    int chunk = pos >> 6, l = pos & 63;
    int kt2 = chunk >> 1, dh = chunk & 1;
    int qd = l >> 4, lv = l & 15;
    short8 tmp;
#pragma unroll
    for (int j = 0; j < 8; ++j)
      tmp[j] = (short)vh[(kt2 * 32 + qd * 8 + j) * 32 + dh * 16 + lv];
    *(short8*)(vfrag + pos * 8) = tmp;
  }
#endif
  __syncthreads();

  for (int t = w; t < 14; t += 4) {
    int r0 = t * 16;
    const ushort* rf = rpbf  + ((size_t)(h * 196 + t * 14) * 64 + lane) * 4;
    const ushort* mf = maskf + ((size_t)(g * 196 + t * 14) * 64 + lane) * 4;
    // q as B operand: B[k=d][n=i]: q[i0+l16][quad*8+..] — same coalesced load
    short8 aq = *(const short8*)(qh + (r0 + l16) * 32 + quad * 8);

    // S^T tiles: lane holds S[i0+l16][jt*16 + quad*4 + r]
    float4_ st[14];
#pragma unroll
    for (int jt = 0; jt < 14; ++jt) {
      ushort4_ rb = *(const ushort4_*)(rf + jt * 256);
      ushort4_ mb = *(const ushort4_*)(mf + jt * 256);
      float4_ cin;
#pragma unroll
      for (int r = 0; r < 4; ++r) cin[r] = bf2f(rb[r]) + bf2f(mb[r]);
      short8 bk = *(const short8*)(kh + (jt * 16 + l16) * 32 + quad * 8);
      st[jt] = __builtin_amdgcn_mfma_f32_16x16x32_bf16(bk, aq, cin, 0, 0, 0);
    }

    // softmax over row i = i0+l16 (56 vals/lane, partners at lane^16, lane^32)
    float mx = -1e30f;
#pragma unroll
    for (int jt = 0; jt < 14; ++jt)
#pragma unroll
      for (int r = 0; r < 4; ++r) mx = fmaxf(mx, st[jt][r]);
    mx = fmaxf(mx, __shfl_xor(mx, 16));
    mx = fmaxf(mx, __shfl_xor(mx, 32));
    float sum = 0.f;
#pragma unroll
    for (int jt = 0; jt < 14; ++jt)
#pragma unroll
      for (int r = 0; r < 4; ++r) {
        float pe = __expf(st[jt][r] - mx);
        st[jt][r] = pe;
        sum += pe;
      }
    sum += __shfl_xor(sum, 16);
    sum += __shfl_xor(sum, 32);
    float inv = 1.0f / sum;   // for row l16; applied to O at the end

    float4_ o0 = (float4_){0.f, 0.f, 0.f, 0.f};
    float4_ o1 = (float4_){0.f, 0.f, 0.f, 0.f};

#if HAVE_MFMA16
    // P·V with 16x16x16: A-frag = packed S^T C-frag (4 bf16), B from vfrag
#pragma unroll
    for (int kt = 0; kt < 14; ++kt) {
      short4_ pa;
#pragma unroll
      for (int r = 0; r < 4; ++r) pa[r] = (short)f2bf(st[kt][r]);
      short4_ vb0 = *(const short4_*)(vfrag + ((kt * 2 + 0) * 64 + lane) * 4);
      short4_ vb1 = *(const short4_*)(vfrag + ((kt * 2 + 1) * 64 + lane) * 4);
      o0 = MFMA16(pa, vb0, o0);
      o1 = MFMA16(pa, vb1, o1);
    }
#else
    // fallback: combine tile pairs into x32 A-frags via cross-quad shuffles
#pragma unroll
    for (int kt2 = 0; kt2 < 7; ++kt2) {
      uint pe0 = ((uint)f2bf(st[2*kt2][0])) | (((uint)f2bf(st[2*kt2][1])) << 16);
      uint pe1 = ((uint)f2bf(st[2*kt2][2])) | (((uint)f2bf(st[2*kt2][3])) << 16);
      uint po0 = ((uint)f2bf(st[2*kt2+1][0])) | (((uint)f2bf(st[2*kt2+1][1])) << 16);
      uint po1 = ((uint)f2bf(st[2*kt2+1][2])) | (((uint)f2bf(st[2*kt2+1][3])) << 16);
      int slo = (((2 * quad) & 3) << 4) | l16;
      int shi = (((2 * quad + 1) & 3) << 4) | l16;
      uint e_lo0 = __shfl((int)pe0, slo), e_lo1 = __shfl((int)pe1, slo);
      uint o_lo0 = __shfl((int)po0, slo), o_lo1 = __shfl((int)po1, slo);
      uint e_hi0 = __shfl((int)pe0, shi), e_hi1 = __shfl((int)pe1, shi);
      uint o_hi0 = __shfl((int)po0, shi), o_hi1 = __shfl((int)po1, shi);
      uint lo0 = (quad < 2) ? e_lo0 : o_lo0, lo1 = (quad < 2) ? e_lo1 : o_lo1;
      uint hi0 = (quad < 2) ? e_hi0 : o_hi0, hi1 = (quad < 2) ? e_hi1 : o_hi1;
      uint4 paw = {lo0, lo1, hi0, hi1};
      short8 pa = __builtin_bit_cast(short8, paw);
      short8 vb0 = *(const short8*)(vfrag + ((kt2 * 2 + 0) * 64 + lane) * 8);
      short8 vb1 = *(const short8*)(vfrag + ((kt2 * 2 + 1) * 64 + lane) * 8);
      o0 = __builtin_amdgcn_mfma_f32_16x16x32_bf16(pa, vb0, o0, 0, 0, 0);
      o1 = __builtin_amdgcn_mfma_f32_16x16x32_bf16(pa, vb1, o1, 0, 0, 0);
    }
#endif

    // apply deferred 1/sum (row of o[r] is i0+quad*4+r, inv lives at lane quad*4+r)
#pragma unroll
    for (int r = 0; r < 4; ++r) {
      float ir = __shfl(inv, quad * 4 + r);
      int i = r0 + quad * 4 + r;
      if (i < 216) {
        size_t base = ((size_t)b * 216 + i) * 192 + h * 32;
        opre[base + l16]      = f2bf(o0[r] * ir);
        opre[base + 16 + l16] = f2bf(o1[r] * ir);
      }
    }
  }
}

// =====================================================================
// launch
// =====================================================================
extern "C" void kernel_launch(void* const* d_in, const int* in_sizes, int n_in,
                              void* d_out, int out_size, void* d_ws, size_t ws_size,
                              hipStream_t stream) {
  (void)in_sizes; (void)n_in; (void)out_size; (void)ws_size;

  char* p = (char*)d_ws;
  int*    flag   = (int*)p;            p += 256;
  ushort* warena = (ushort*)p;         p += 298240;
  float*  pos    = (float*)p;          p += 32768;
  ushort* rpbf   = (ushort*)p;         p += 602112;    // 6*196*64*4*2
  ushort* maskf  = (ushort*)p;         p += 6422528;   // 64*196*64*4*2
  ushort* ycvt   = (ushort*)p;         p += 21234688;  // aliased as opre after QKV GEMM
  ushort* qb     = (ushort*)p;         p += 21234688;
  ushort* kb     = (ushort*)p;         p += 21234688;
  ushort* vb     = (ushort*)p;
  ushort* opre   = ycvt;

  detect_kernel<<<1, 64, 0, stream>>>((const uint*)d_in[0], flag);

  SrcPtrs sp;
  for (int i = 0; i < 18; ++i) sp.p[i] = d_in[3 + i];
  convert_kernel<<<(WA_TOTAL + 255) / 256, 256, 0, stream>>>(sp, warena, flag);

  cvt_kernel<<<5184, 256, 0, stream>>>((const float*)d_in[1], ycvt, flag);

  pos_mlp_kernel<<<6, 256, 0, stream>>>(warena, pos);
  rpbfrag_kernel<<<294, 256, 0, stream>>>(pos, rpbf);
  maskfrag_kernel<<<3136, 256, 0, stream>>>(d_in[2], flag, maskf);

  gemm_kernel<<<dim3(432, 2, 3), 256, 0, stream>>>(
      d_in[0], ycvt, d_in[1], warena + WA_WQKV, warena + WA_BQKV,
      qb, kb, vb, flag, 0);

  attn_kernel<<<1536, 256, 0, stream>>>(qb, kb, vb, rpbf, maskf, opre);

  gemm_kernel<<<dim3(432, 2, 1), 256, 0, stream>>>(
      opre, opre, opre, warena + WA_WPROJ, warena + WA_BPROJ,
      d_out, d_out, d_out, flag, 1);
}